// Round 18
// baseline (201.496 us; speedup 1.0000x reference)
//
#include <hip/hip_runtime.h>

#define FIN 256
#define H1 8
#define C1 16
#define D1 128   // H1*C1
#define D2 40
#define D2P 48

#define BW_LOG 8
#define BWIDTH 256           // nodes per bucket
#define B1 1024              // scatter blocks
#define CHMAX 1600           // staging capacity (ceil(E/B1)=1563)
#define CAP 10240            // per-bucket region capacity

typedef float f32x4 __attribute__((ext_vector_type(4)));
typedef short bf16x8 __attribute__((ext_vector_type(8)));

static __device__ __forceinline__ float lrelu(float x){ return fmaxf(x, 0.2f*x); }
static __device__ __forceinline__ float elu(float x){ return x > 0.f ? x : __expf(x) - 1.f; }
static __device__ __forceinline__ unsigned short f2bf(float f){      // RNE bf16
  unsigned u = __float_as_uint(f);
  return (unsigned short)((u + 0x7fffu + ((u >> 16) & 1u)) >> 16);
}
static __device__ __forceinline__ float bf_lo(unsigned v){ return __uint_as_float(v << 16); }
static __device__ __forceinline__ float bf_hi(unsigned v){ return __uint_as_float(v & 0xffff0000u); }
static __device__ __forceinline__ bf16x8 pack_bf8(float4 a, float4 b){
  bf16x8 r;
  r[0]=(short)f2bf(a.x); r[1]=(short)f2bf(a.y); r[2]=(short)f2bf(a.z); r[3]=(short)f2bf(a.w);
  r[4]=(short)f2bf(b.x); r[5]=(short)f2bf(b.y); r[6]=(short)f2bf(b.z); r[7]=(short)f2bf(b.w);
  return r;
}

// ---------------- F1: wt (128 blocks) ∪ wt2 (24) ∪ gcur init (1) ----------------
__global__ __launch_bounds__(256) void f1_k(const float* __restrict__ W1, unsigned short* __restrict__ W1T,
                                            const float* __restrict__ W2, unsigned short* __restrict__ W2T,
                                            int* __restrict__ gcur, int NB){
  int b = blockIdx.x, t = threadIdx.x;
  if (b < 128){
    W1T[b*FIN + t] = f2bf(W1[(size_t)t*D1 + b]);
  } else if (b < 152){
    int c = (b - 128)*2 + (t >> 7);
    int k = t & 127;
    float v = (c < D2) ? W2[(size_t)k*D2 + c] : 0.f;
    W2T[c*D1 + k] = f2bf(v);
  } else {
    if (t < NB) gcur[t] = t*CAP;
  }
}

// ---------------- F3: ticket-scatter (blocks 0..B1, ~9.6KB LDS) ∪ gemm1 (blocks B1..) ----------------
__global__ __launch_bounds__(256) void f3_k(
    // gemm1 args
    const float* __restrict__ x, const unsigned short* __restrict__ W1T,
    const float* __restrict__ attS, const float* __restrict__ attD,
    unsigned short* __restrict__ h1b, float* __restrict__ aS, float* __restrict__ aD, int N,
    // scatter args
    const int* __restrict__ src, const int* __restrict__ dst, int E, int NB,
    int* __restrict__ gcur, int* __restrict__ bucketEdges){
  int tid = threadIdx.x;
  if ((int)blockIdx.x < B1){
    // ---- scatter: LDS hist -> per-bucket ticket -> LDS sort (packed src|dst, unsigned) -> coalesced out ----
    __shared__ int lhist[256];
    __shared__ int lscan[256];
    __shared__ int gbase[256];
    __shared__ unsigned stage[CHMAX];
    int blk = blockIdx.x;
    lhist[tid] = 0;
    __syncthreads();
    int CH = (E + B1 - 1) / B1;
    int lo = blk*CH, hi = min(E, lo + CH), cnt = hi - lo;
    if (cnt <= CHMAX){
      for (int i = lo + tid; i < hi; i += 256)
        atomicAdd(&lhist[dst[i] >> BW_LOG], 1);
      __syncthreads();
      int lv = lhist[tid];
      if (tid < NB && lv > 0) gbase[tid] = atomicAdd(&gcur[tid], lv);
      lscan[tid] = lv; __syncthreads();
      for (int o = 1; o < 256; o <<= 1){
        int u = (tid >= o) ? lscan[tid-o] : 0;
        __syncthreads();
        lscan[tid] += u;
        __syncthreads();
      }
      int excl = lscan[tid] - lv;
      __syncthreads();
      lscan[tid] = excl;           // slot base per bucket
      lhist[tid] = excl;           // cursor
      __syncthreads();
      // LDS scatter into bucket order, packed unsigned (src<<16 | dst)
      for (int i = lo + tid; i < hi; i += 256){
        int dd = dst[i];
        int b = dd >> BW_LOG;
        int p = atomicAdd(&lhist[b], 1);
        stage[p] = ((unsigned)src[i] << 16) | (unsigned)dd;
      }
      __syncthreads();
      // coalesced write-out (logical shifts on unsigned)
      for (int s = tid; s < cnt; s += 256){
        unsigned v = stage[s];
        unsigned dd = v & 0xFFFFu;
        int b = (int)(dd >> BW_LOG);
        bucketEdges[gbase[b] + (s - lscan[b])] = (int)(((v >> 16) << BW_LOG) | (dd & (BWIDTH-1)));
      }
    } else {
      // fallback: direct scatter via global tickets
      if (tid < NB) lhist[tid] = 0;
      __syncthreads();
      for (int i = lo + tid; i < hi; i += 256)
        atomicAdd(&lhist[dst[i] >> BW_LOG], 1);
      __syncthreads();
      int lv = lhist[tid];
      if (tid < NB && lv > 0) gbase[tid] = atomicAdd(&gcur[tid], lv);
      if (tid < NB) lhist[tid] = 0;
      __syncthreads();
      for (int i = lo + tid; i < hi; i += 256){
        int dd = dst[i];
        int b = dd >> BW_LOG;
        int p = atomicAdd(&lhist[b], 1);
        bucketEdges[gbase[b] + p] = (src[i] << BW_LOG) | (dd & (BWIDTH-1));
      }
    }
    return;
  }
  // ---- gemm1 ----
  int w = tid >> 6, lane = tid & 63;
  int lr = lane & 15, lg = lane >> 4;
  int wm = w >> 1, wn = w & 1;
  int m0 = ((int)blockIdx.x - B1) * 64;

  int rowA[2];
  #pragma unroll
  for (int mi=0;mi<2;mi++){
    int r = m0 + wm*32 + mi*16 + lr;
    rowA[mi] = (r < N) ? r : (N-1);
  }

  f32x4 acc[2][4];
  #pragma unroll
  for (int mi=0;mi<2;mi++)
    #pragma unroll
    for (int ni=0;ni<4;ni++) acc[mi][ni] = (f32x4){0.f,0.f,0.f,0.f};

  #pragma unroll
  for (int ks = 0; ks < 8; ++ks){
    int k0 = ks*32 + lg*8;
    bf16x8 a[2], b[4];
    #pragma unroll
    for (int mi=0;mi<2;mi++){
      const float* px = x + (size_t)rowA[mi]*FIN + k0;
      float4 v0 = *(const float4*)px;
      float4 v1 = *(const float4*)(px+4);
      a[mi] = pack_bf8(v0, v1);
    }
    #pragma unroll
    for (int ni=0;ni<4;ni++){
      int col = wn*64 + ni*16 + lr;
      b[ni] = *(const bf16x8*)(W1T + (size_t)col*FIN + k0);
    }
    #pragma unroll
    for (int mi=0;mi<2;mi++)
      #pragma unroll
      for (int ni=0;ni<4;ni++)
        acc[mi][ni] = __builtin_amdgcn_mfma_f32_16x16x32_bf16(a[mi], b[ni], acc[mi][ni], 0, 0, 0);
  }

  #pragma unroll
  for (int mi=0;mi<2;mi++){
    #pragma unroll
    for (int ni=0;ni<4;ni++){
      int h = wn*4 + ni;
      int col = wn*64 + ni*16 + lr;
      float sS = attS[h*C1 + lr], sD = attD[h*C1 + lr];
      #pragma unroll
      for (int i=0;i<4;i++){
        int row = m0 + wm*32 + mi*16 + 4*lg + i;
        float v = acc[mi][ni][i];
        float pS = v*sS, pD = v*sD;
        pS += __shfl_xor(pS, 1); pD += __shfl_xor(pD, 1);
        pS += __shfl_xor(pS, 2); pD += __shfl_xor(pD, 2);
        pS += __shfl_xor(pS, 4); pD += __shfl_xor(pD, 4);
        pS += __shfl_xor(pS, 8); pD += __shfl_xor(pD, 8);
        if (row < N){
          h1b[(size_t)row*D1 + col] = f2bf(v);
          if (lr == 0){ aS[row*H1 + h] = pS; aD[row*H1 + h] = pD; }
        }
      }
    }
  }
}

// p2: counts from gcur, inline scan; builds off + csr from fixed-capacity regions
__global__ __launch_bounds__(BWIDTH) void p2_k(const int* __restrict__ bucketEdges,
                                               const int* __restrict__ gcur, int NB,
                                               int* __restrict__ off, int* __restrict__ csr, int N){
  __shared__ int deg[BWIDTH];
  __shared__ int s[BWIDTH];
  __shared__ int cur[BWIDTH];
  __shared__ int sb[BWIDTH];
  int b = blockIdx.x, t = threadIdx.x;
  int vc = (t < NB) ? (gcur[t] - t*CAP) : 0;
  sb[t] = vc; __syncthreads();
  for (int o = 1; o < BWIDTH; o <<= 1){
    int u = (t >= o) ? sb[t-o] : 0;
    __syncthreads();
    sb[t] += u;
    __syncthreads();
  }
  int e0 = (b > 0) ? sb[b-1] : 0;
  int cntb = sb[b] - e0;
  if (b == 0 && t == 0) off[N] = sb[NB-1];
  size_t rb = (size_t)b*CAP;
  deg[t] = 0;
  __syncthreads();
  for (int i = t; i < cntb; i += BWIDTH)
    atomicAdd(&deg[bucketEdges[rb + i] & (BWIDTH-1)], 1);
  __syncthreads();
  int v = deg[t];
  s[t] = v; __syncthreads();
  for (int o = 1; o < BWIDTH; o <<= 1){
    int u = (t >= o) ? s[t-o] : 0;
    __syncthreads();
    s[t] += u;
    __syncthreads();
  }
  int excl = s[t] - v;
  int node = b*BWIDTH + t;
  if (node < N) off[node] = e0 + excl;
  cur[t] = excl;
  __syncthreads();
  for (int i = t; i < cntb; i += BWIDTH){
    int pk = bucketEdges[rb + i];
    int p = atomicAdd(&cur[pk & (BWIDTH-1)], 1);
    csr[e0 + p] = pk >> BW_LOG;
  }
}

// ---------------- GEMM2 via MFMA, pure bf16 ----------------
__global__ __launch_bounds__(256) void gemm2_mfma(const unsigned short* __restrict__ x2b,
    const unsigned short* __restrict__ W2T,
    const float* __restrict__ attS2, const float* __restrict__ attD2,
    unsigned short* __restrict__ h2b, float* __restrict__ aS2, float* __restrict__ aD2, int N){
  int tid = threadIdx.x;
  int w = tid >> 6, lane = tid & 63;
  int lr = lane & 15, lg = lane >> 4;
  int m0 = blockIdx.x*128 + w*32;

  int rowA[2];
  #pragma unroll
  for (int mi=0;mi<2;mi++){
    int r = m0 + mi*16 + lr;
    rowA[mi] = (r < N) ? r : (N-1);
  }

  f32x4 acc[2][3];
  #pragma unroll
  for (int mi=0;mi<2;mi++)
    #pragma unroll
    for (int ni=0;ni<3;ni++) acc[mi][ni] = (f32x4){0.f,0.f,0.f,0.f};

  #pragma unroll
  for (int ks = 0; ks < 4; ++ks){
    int k0 = ks*32 + lg*8;
    bf16x8 a[2], b[3];
    #pragma unroll
    for (int mi=0;mi<2;mi++)
      a[mi] = *(const bf16x8*)(x2b + (size_t)rowA[mi]*D1 + k0);
    #pragma unroll
    for (int ni=0;ni<3;ni++){
      int col = ni*16 + lr;
      b[ni] = *(const bf16x8*)(W2T + (size_t)col*D1 + k0);
    }
    #pragma unroll
    for (int mi=0;mi<2;mi++)
      #pragma unroll
      for (int ni=0;ni<3;ni++)
        acc[mi][ni] = __builtin_amdgcn_mfma_f32_16x16x32_bf16(a[mi], b[ni], acc[mi][ni], 0, 0, 0);
  }

  float attSv[3], attDv[3];
  #pragma unroll
  for (int ni=0;ni<3;ni++){
    int col = ni*16 + lr;
    attSv[ni] = (col < D2) ? attS2[col] : 0.f;
    attDv[ni] = (col < D2) ? attD2[col] : 0.f;
  }
  #pragma unroll
  for (int mi=0;mi<2;mi++){
    #pragma unroll
    for (int i=0;i<4;i++){
      int row = m0 + mi*16 + 4*lg + i;
      float pS = 0.f, pD = 0.f;
      #pragma unroll
      for (int ni=0;ni<3;ni++){
        pS += acc[mi][ni][i]*attSv[ni];
        pD += acc[mi][ni][i]*attDv[ni];
      }
      pS += __shfl_xor(pS, 1); pD += __shfl_xor(pD, 1);
      pS += __shfl_xor(pS, 2); pD += __shfl_xor(pD, 2);
      pS += __shfl_xor(pS, 4); pD += __shfl_xor(pD, 4);
      pS += __shfl_xor(pS, 8); pD += __shfl_xor(pD, 8);
      if (row < N){
        #pragma unroll
        for (int ni=0;ni<3;ni++){
          int col = ni*16 + lr;
          if (col < D2) h2b[(size_t)row*D2 + col] = f2bf(acc[mi][ni][i]);
        }
        if (lr == 0){ aS2[row] = pS; aD2[row] = pD; }
      }
    }
  }
}

// ---------------- node1: softmax aggregation over bf16 h1 -> bf16 x2 ----------------
__global__ __launch_bounds__(64) void node1_k(const unsigned short* __restrict__ h1b,
    const float* __restrict__ aS, const float* __restrict__ aD,
    const int* __restrict__ off, const int* __restrict__ csr,
    const float* __restrict__ b1, unsigned short* __restrict__ x2b, int N){
  int n = blockIdx.x;
  int lane = threadIdx.x;
  int c = lane*2;                 // channels c, c+1
  int h = lane >> 3;              // head = c/16
  float ad = aD[n*H1+h];
  float p = __expf(lrelu(aS[n*H1+h] + ad));   // self loop
  float d = p;
  unsigned hv = *(const unsigned*)&h1b[(size_t)n*D1 + c];
  float acc0 = p*bf_lo(hv), acc1 = p*bf_hi(hv);
  int i = off[n], e = off[n+1];
  for (; i < e && (i & 3); ++i){
    int s = csr[i];
    float pp = __expf(lrelu(aS[s*H1+h] + ad));
    unsigned vv = *(const unsigned*)&h1b[(size_t)s*D1 + c];
    d += pp; acc0 += pp*bf_lo(vv); acc1 += pp*bf_hi(vv);
  }
  for (; i+8 <= e; i += 8){
    int4 ca = *(const int4*)&csr[i];
    int4 cb = *(const int4*)&csr[i+4];
    int s[8] = {ca.x,ca.y,ca.z,ca.w,cb.x,cb.y,cb.z,cb.w};
    float a[8]; unsigned v[8];
    #pragma unroll
    for (int u=0;u<8;u++) a[u] = aS[s[u]*H1+h];
    #pragma unroll
    for (int u=0;u<8;u++) v[u] = *(const unsigned*)&h1b[(size_t)s[u]*D1 + c];
    #pragma unroll
    for (int u=0;u<8;u++){
      float pp = __expf(lrelu(a[u]+ad));
      d += pp; acc0 += pp*bf_lo(v[u]); acc1 += pp*bf_hi(v[u]);
    }
  }
  for (; i < e; ++i){
    int s = csr[i];
    float pp = __expf(lrelu(aS[s*H1+h] + ad));
    unsigned vv = *(const unsigned*)&h1b[(size_t)s*D1 + c];
    d += pp; acc0 += pp*bf_lo(vv); acc1 += pp*bf_hi(vv);
  }
  float inv = 1.f/d;
  float o0 = elu(acc0*inv + b1[c]);
  float o1 = elu(acc1*inv + b1[c+1]);
  unsigned pk = (unsigned)f2bf(o0) | ((unsigned)f2bf(o1) << 16);
  *(unsigned*)&x2b[(size_t)n*D1 + c] = pk;
}

// ---------------- node2: 3 nodes per wave (20 lanes each) ----------------
__global__ __launch_bounds__(64) void node2_k(const unsigned short* __restrict__ h2b,
    const float* __restrict__ aS2, const float* __restrict__ aD2,
    const int* __restrict__ off, const int* __restrict__ csr,
    const float* __restrict__ b2, float* __restrict__ out, int N){
  int lane = threadIdx.x;
  int g = lane / 20;              // 0..3 (g==3 idle)
  int l = lane - g*20;            // 0..19
  int n = blockIdx.x*3 + g;
  if (g >= 3 || n >= N) return;
  int c = l*2;
  float ad = aD2[n];
  float ps = __expf(lrelu(aS2[n] + ad));   // self loop
  float d = ps;
  unsigned v0 = *(const unsigned*)&h2b[(size_t)n*D2 + c];
  float acc0 = ps*bf_lo(v0), acc1 = ps*bf_hi(v0);
  int i = off[n], e = off[n+1];
  for (; i < e && (i & 3); ++i){
    int s = csr[i];
    float pp = __expf(lrelu(aS2[s] + ad));
    unsigned vv = *(const unsigned*)&h2b[(size_t)s*D2 + c];
    d += pp; acc0 += pp*bf_lo(vv); acc1 += pp*bf_hi(vv);
  }
  for (; i+8 <= e; i += 8){
    int4 ca = *(const int4*)&csr[i];
    int4 cb = *(const int4*)&csr[i+4];
    int s[8] = {ca.x,ca.y,ca.z,ca.w,cb.x,cb.y,cb.z,cb.w};
    float a[8]; unsigned v[8];
    #pragma unroll
    for (int u=0;u<8;u++) a[u] = aS2[s[u]];
    #pragma unroll
    for (int u=0;u<8;u++) v[u] = *(const unsigned*)&h2b[(size_t)s[u]*D2 + c];
    #pragma unroll
    for (int u=0;u<8;u++){
      float pp = __expf(lrelu(a[u]+ad));
      d += pp; acc0 += pp*bf_lo(v[u]); acc1 += pp*bf_hi(v[u]);
    }
  }
  for (; i < e; ++i){
    int s = csr[i];
    float pp = __expf(lrelu(aS2[s] + ad));
    unsigned vv = *(const unsigned*)&h2b[(size_t)s*D2 + c];
    d += pp; acc0 += pp*bf_lo(vv); acc1 += pp*bf_hi(vv);
  }
  float inv = 1.f/d;
  float2 o;
  o.x = acc0*inv + b2[c];
  o.y = acc1*inv + b2[c+1];
  *(float2*)&out[(size_t)n*D2 + c] = o;
}

extern "C" void kernel_launch(void* const* d_in, const int* in_sizes, int n_in,
                              void* d_out, int out_size, void* d_ws, size_t ws_size,
                              hipStream_t stream){
  const float* x     = (const float*)d_in[0];
  const int*   ei    = (const int*)d_in[1];
  const float* W1    = (const float*)d_in[2];
  const float* attS1 = (const float*)d_in[3];
  const float* attD1 = (const float*)d_in[4];
  const float* b1    = (const float*)d_in[5];
  const float* W2    = (const float*)d_in[6];
  const float* attS2 = (const float*)d_in[7];
  const float* attD2 = (const float*)d_in[8];
  const float* b2    = (const float*)d_in[9];
  float* out = (float*)d_out;

  int N = in_sizes[0] / FIN;   // 50000
  int E = in_sizes[1] / 2;     // 1600000
  const int* src = ei;
  const int* dst = ei + E;
  int NB = (N + BWIDTH - 1) >> BW_LOG;    // 196

  char* ws = (char*)d_ws;
  size_t o = 0;
  auto alloc = [&](size_t bytes) -> void* {
    void* p = ws + o;
    o += (bytes + 255) & ~size_t(255);
    return p;
  };
  unsigned short* h1b = (unsigned short*)alloc((size_t)N*D1*sizeof(unsigned short));
  unsigned short* x2b = (unsigned short*)alloc((size_t)N*D1*sizeof(unsigned short));
  unsigned short* h2b = (unsigned short*)alloc((size_t)N*D2*sizeof(unsigned short));
  float* aS1   = (float*)alloc((size_t)N*H1*sizeof(float));
  float* aD1   = (float*)alloc((size_t)N*H1*sizeof(float));
  float* aS2   = (float*)alloc((size_t)N*sizeof(float));
  float* aD2   = (float*)alloc((size_t)N*sizeof(float));
  int*   off   = (int*)alloc((size_t)(N+1)*sizeof(int));
  int*   csr   = (int*)alloc((size_t)E*sizeof(int));
  int*   gcur  = (int*)alloc((size_t)256*sizeof(int));
  int*   bucketEdges = (int*)alloc((size_t)NB*CAP*sizeof(int));
  unsigned short* W1T = (unsigned short*)alloc((size_t)D1*FIN*sizeof(unsigned short));
  unsigned short* W2T = (unsigned short*)alloc((size_t)D2P*D1*sizeof(unsigned short));

  int G1 = (N + 63) / 64;      // gemm1 blocks = 782

  f1_k<<<153, 256, 0, stream>>>(W1, W1T, W2, W2T, gcur, NB);
  f3_k<<<B1 + G1, 256, 0, stream>>>(x, W1T, attS1, attD1, h1b, aS1, aD1, N,
                                    src, dst, E, NB, gcur, bucketEdges);
  p2_k<<<NB, BWIDTH, 0, stream>>>(bucketEdges, gcur, NB, off, csr, N);
  node1_k<<<N, 64, 0, stream>>>(h1b, aS1, aD1, off, csr, b1, x2b, N);
  gemm2_mfma<<<(N+127)/128, 256, 0, stream>>>(x2b, W2T, attS2, attD2, h2b, aS2, aD2, N);
  node2_k<<<(N+2)/3, 64, 0, stream>>>(h2b, aS2, aD2, off, csr, b2, out, N);
}

// Round 19
// 184.404 us; speedup vs baseline: 1.0927x; 1.0927x over previous
//
#include <hip/hip_runtime.h>

#define FIN 256
#define H1 8
#define C1 16
#define D1 128   // H1*C1
#define D2 40
#define D2P 48

#define BW_LOG 8
#define BWIDTH 256           // nodes per bucket
#define B1 512               // scatter blocks
#define CHMAX 3200           // staging capacity (E/B1 = 3125)
#define CAP 10240            // per-bucket region capacity

typedef float f32x4 __attribute__((ext_vector_type(4)));
typedef short bf16x8 __attribute__((ext_vector_type(8)));

static __device__ __forceinline__ float lrelu(float x){ return fmaxf(x, 0.2f*x); }
static __device__ __forceinline__ float elu(float x){ return x > 0.f ? x : __expf(x) - 1.f; }
static __device__ __forceinline__ unsigned short f2bf(float f){      // RNE bf16
  unsigned u = __float_as_uint(f);
  return (unsigned short)((u + 0x7fffu + ((u >> 16) & 1u)) >> 16);
}
static __device__ __forceinline__ float bf_lo(unsigned v){ return __uint_as_float(v << 16); }
static __device__ __forceinline__ float bf_hi(unsigned v){ return __uint_as_float(v & 0xffff0000u); }
static __device__ __forceinline__ bf16x8 pack_bf8(float4 a, float4 b){
  bf16x8 r;
  r[0]=(short)f2bf(a.x); r[1]=(short)f2bf(a.y); r[2]=(short)f2bf(a.z); r[3]=(short)f2bf(a.w);
  r[4]=(short)f2bf(b.x); r[5]=(short)f2bf(b.y); r[6]=(short)f2bf(b.z); r[7]=(short)f2bf(b.w);
  return r;
}

// ---------------- F1: wt (128 blocks) ∪ wt2 (24) ∪ gcur init (1) ----------------
__global__ __launch_bounds__(256) void f1_k(const float* __restrict__ W1, unsigned short* __restrict__ W1T,
                                            const float* __restrict__ W2, unsigned short* __restrict__ W2T,
                                            int* __restrict__ gcur, int NB){
  int b = blockIdx.x, t = threadIdx.x;
  if (b < 128){
    W1T[b*FIN + t] = f2bf(W1[(size_t)t*D1 + b]);
  } else if (b < 152){
    int c = (b - 128)*2 + (t >> 7);
    int k = t & 127;
    float v = (c < D2) ? W2[(size_t)k*D2 + c] : 0.f;
    W2T[c*D1 + k] = f2bf(v);
  } else {
    if (t < NB) gcur[t] = t*CAP;
  }
}

// ---------------- F3: gemm1 (blocks 0..G1, dispatched FIRST) ∪ ticket-scatter (blocks G1..G1+B1) ----------------
__global__ __launch_bounds__(256) void f3_k(
    // gemm1 args
    const float* __restrict__ x, const unsigned short* __restrict__ W1T,
    const float* __restrict__ attS, const float* __restrict__ attD,
    unsigned short* __restrict__ h1b, float* __restrict__ aS, float* __restrict__ aD, int N, int G1,
    // scatter args
    const int* __restrict__ src, const int* __restrict__ dst, int E, int NB,
    int* __restrict__ gcur, int* __restrict__ bucketEdges){
  int tid = threadIdx.x;
  if ((int)blockIdx.x >= G1){
    // ---- scatter: LDS hist -> per-bucket ticket -> LDS sort (packed src|dst, unsigned) -> coalesced out ----
    __shared__ int lhist[256];
    __shared__ int lscan[256];
    __shared__ int gbase[256];
    __shared__ unsigned stage[CHMAX];
    int blk = (int)blockIdx.x - G1;
    lhist[tid] = 0;
    __syncthreads();
    int CH = (E + B1 - 1) / B1;
    int lo = blk*CH, hi = min(E, lo + CH), cnt = hi - lo;
    if (cnt <= CHMAX){
      for (int i = lo + tid; i < hi; i += 256)
        atomicAdd(&lhist[dst[i] >> BW_LOG], 1);
      __syncthreads();
      int lv = lhist[tid];
      if (tid < NB && lv > 0) gbase[tid] = atomicAdd(&gcur[tid], lv);
      lscan[tid] = lv; __syncthreads();
      for (int o = 1; o < 256; o <<= 1){
        int u = (tid >= o) ? lscan[tid-o] : 0;
        __syncthreads();
        lscan[tid] += u;
        __syncthreads();
      }
      int excl = lscan[tid] - lv;
      __syncthreads();
      lscan[tid] = excl;           // slot base per bucket
      lhist[tid] = excl;           // cursor
      __syncthreads();
      // LDS scatter into bucket order, packed unsigned (src<<16 | dst)
      for (int i = lo + tid; i < hi; i += 256){
        int dd = dst[i];
        int b = dd >> BW_LOG;
        int p = atomicAdd(&lhist[b], 1);
        stage[p] = ((unsigned)src[i] << 16) | (unsigned)dd;
      }
      __syncthreads();
      // coalesced write-out (logical shifts on unsigned)
      for (int s = tid; s < cnt; s += 256){
        unsigned v = stage[s];
        unsigned dd = v & 0xFFFFu;
        int b = (int)(dd >> BW_LOG);
        bucketEdges[gbase[b] + (s - lscan[b])] = (int)(((v >> 16) << BW_LOG) | (dd & (BWIDTH-1)));
      }
    } else {
      // fallback: direct scatter via global tickets
      if (tid < NB) lhist[tid] = 0;
      __syncthreads();
      for (int i = lo + tid; i < hi; i += 256)
        atomicAdd(&lhist[dst[i] >> BW_LOG], 1);
      __syncthreads();
      int lv = lhist[tid];
      if (tid < NB && lv > 0) gbase[tid] = atomicAdd(&gcur[tid], lv);
      if (tid < NB) lhist[tid] = 0;
      __syncthreads();
      for (int i = lo + tid; i < hi; i += 256){
        int dd = dst[i];
        int b = dd >> BW_LOG;
        int p = atomicAdd(&lhist[b], 1);
        bucketEdges[gbase[b] + p] = (src[i] << BW_LOG) | (dd & (BWIDTH-1));
      }
    }
    return;
  }
  // ---- gemm1 ----
  int w = tid >> 6, lane = tid & 63;
  int lr = lane & 15, lg = lane >> 4;
  int wm = w >> 1, wn = w & 1;
  int m0 = (int)blockIdx.x * 64;

  int rowA[2];
  #pragma unroll
  for (int mi=0;mi<2;mi++){
    int r = m0 + wm*32 + mi*16 + lr;
    rowA[mi] = (r < N) ? r : (N-1);
  }

  f32x4 acc[2][4];
  #pragma unroll
  for (int mi=0;mi<2;mi++)
    #pragma unroll
    for (int ni=0;ni<4;ni++) acc[mi][ni] = (f32x4){0.f,0.f,0.f,0.f};

  #pragma unroll
  for (int ks = 0; ks < 8; ++ks){
    int k0 = ks*32 + lg*8;
    bf16x8 a[2], b[4];
    #pragma unroll
    for (int mi=0;mi<2;mi++){
      const float* px = x + (size_t)rowA[mi]*FIN + k0;
      float4 v0 = *(const float4*)px;
      float4 v1 = *(const float4*)(px+4);
      a[mi] = pack_bf8(v0, v1);
    }
    #pragma unroll
    for (int ni=0;ni<4;ni++){
      int col = wn*64 + ni*16 + lr;
      b[ni] = *(const bf16x8*)(W1T + (size_t)col*FIN + k0);
    }
    #pragma unroll
    for (int mi=0;mi<2;mi++)
      #pragma unroll
      for (int ni=0;ni<4;ni++)
        acc[mi][ni] = __builtin_amdgcn_mfma_f32_16x16x32_bf16(a[mi], b[ni], acc[mi][ni], 0, 0, 0);
  }

  #pragma unroll
  for (int mi=0;mi<2;mi++){
    #pragma unroll
    for (int ni=0;ni<4;ni++){
      int h = wn*4 + ni;
      int col = wn*64 + ni*16 + lr;
      float sS = attS[h*C1 + lr], sD = attD[h*C1 + lr];
      #pragma unroll
      for (int i=0;i<4;i++){
        int row = m0 + wm*32 + mi*16 + 4*lg + i;
        float v = acc[mi][ni][i];
        float pS = v*sS, pD = v*sD;
        pS += __shfl_xor(pS, 1); pD += __shfl_xor(pD, 1);
        pS += __shfl_xor(pS, 2); pD += __shfl_xor(pD, 2);
        pS += __shfl_xor(pS, 4); pD += __shfl_xor(pD, 4);
        pS += __shfl_xor(pS, 8); pD += __shfl_xor(pD, 8);
        if (row < N){
          h1b[(size_t)row*D1 + col] = f2bf(v);
          if (lr == 0){ aS[row*H1 + h] = pS; aD[row*H1 + h] = pD; }
        }
      }
    }
  }
}

// p2: counts from gcur, inline scan; builds off + csr from fixed-capacity regions
__global__ __launch_bounds__(BWIDTH) void p2_k(const int* __restrict__ bucketEdges,
                                               const int* __restrict__ gcur, int NB,
                                               int* __restrict__ off, int* __restrict__ csr, int N){
  __shared__ int deg[BWIDTH];
  __shared__ int s[BWIDTH];
  __shared__ int cur[BWIDTH];
  __shared__ int sb[BWIDTH];
  int b = blockIdx.x, t = threadIdx.x;
  int vc = (t < NB) ? (gcur[t] - t*CAP) : 0;
  sb[t] = vc; __syncthreads();
  for (int o = 1; o < BWIDTH; o <<= 1){
    int u = (t >= o) ? sb[t-o] : 0;
    __syncthreads();
    sb[t] += u;
    __syncthreads();
  }
  int e0 = (b > 0) ? sb[b-1] : 0;
  int cntb = sb[b] - e0;
  if (b == 0 && t == 0) off[N] = sb[NB-1];
  size_t rb = (size_t)b*CAP;
  deg[t] = 0;
  __syncthreads();
  for (int i = t; i < cntb; i += BWIDTH)
    atomicAdd(&deg[bucketEdges[rb + i] & (BWIDTH-1)], 1);
  __syncthreads();
  int v = deg[t];
  s[t] = v; __syncthreads();
  for (int o = 1; o < BWIDTH; o <<= 1){
    int u = (t >= o) ? s[t-o] : 0;
    __syncthreads();
    s[t] += u;
    __syncthreads();
  }
  int excl = s[t] - v;
  int node = b*BWIDTH + t;
  if (node < N) off[node] = e0 + excl;
  cur[t] = excl;
  __syncthreads();
  for (int i = t; i < cntb; i += BWIDTH){
    int pk = bucketEdges[rb + i];
    int p = atomicAdd(&cur[pk & (BWIDTH-1)], 1);
    csr[e0 + p] = pk >> BW_LOG;
  }
}

// ---------------- GEMM2 via MFMA, pure bf16 ----------------
__global__ __launch_bounds__(256) void gemm2_mfma(const unsigned short* __restrict__ x2b,
    const unsigned short* __restrict__ W2T,
    const float* __restrict__ attS2, const float* __restrict__ attD2,
    unsigned short* __restrict__ h2b, float* __restrict__ aS2, float* __restrict__ aD2, int N){
  int tid = threadIdx.x;
  int w = tid >> 6, lane = tid & 63;
  int lr = lane & 15, lg = lane >> 4;
  int m0 = blockIdx.x*128 + w*32;

  int rowA[2];
  #pragma unroll
  for (int mi=0;mi<2;mi++){
    int r = m0 + mi*16 + lr;
    rowA[mi] = (r < N) ? r : (N-1);
  }

  f32x4 acc[2][3];
  #pragma unroll
  for (int mi=0;mi<2;mi++)
    #pragma unroll
    for (int ni=0;ni<3;ni++) acc[mi][ni] = (f32x4){0.f,0.f,0.f,0.f};

  #pragma unroll
  for (int ks = 0; ks < 4; ++ks){
    int k0 = ks*32 + lg*8;
    bf16x8 a[2], b[3];
    #pragma unroll
    for (int mi=0;mi<2;mi++)
      a[mi] = *(const bf16x8*)(x2b + (size_t)rowA[mi]*D1 + k0);
    #pragma unroll
    for (int ni=0;ni<3;ni++){
      int col = ni*16 + lr;
      b[ni] = *(const bf16x8*)(W2T + (size_t)col*D1 + k0);
    }
    #pragma unroll
    for (int mi=0;mi<2;mi++)
      #pragma unroll
      for (int ni=0;ni<3;ni++)
        acc[mi][ni] = __builtin_amdgcn_mfma_f32_16x16x32_bf16(a[mi], b[ni], acc[mi][ni], 0, 0, 0);
  }

  float attSv[3], attDv[3];
  #pragma unroll
  for (int ni=0;ni<3;ni++){
    int col = ni*16 + lr;
    attSv[ni] = (col < D2) ? attS2[col] : 0.f;
    attDv[ni] = (col < D2) ? attD2[col] : 0.f;
  }
  #pragma unroll
  for (int mi=0;mi<2;mi++){
    #pragma unroll
    for (int i=0;i<4;i++){
      int row = m0 + mi*16 + 4*lg + i;
      float pS = 0.f, pD = 0.f;
      #pragma unroll
      for (int ni=0;ni<3;ni++){
        pS += acc[mi][ni][i]*attSv[ni];
        pD += acc[mi][ni][i]*attDv[ni];
      }
      pS += __shfl_xor(pS, 1); pD += __shfl_xor(pD, 1);
      pS += __shfl_xor(pS, 2); pD += __shfl_xor(pD, 2);
      pS += __shfl_xor(pS, 4); pD += __shfl_xor(pD, 4);
      pS += __shfl_xor(pS, 8); pD += __shfl_xor(pD, 8);
      if (row < N){
        #pragma unroll
        for (int ni=0;ni<3;ni++){
          int col = ni*16 + lr;
          if (col < D2) h2b[(size_t)row*D2 + col] = f2bf(acc[mi][ni][i]);
        }
        if (lr == 0){ aS2[row] = pS; aD2[row] = pD; }
      }
    }
  }
}

// ---------------- node1: softmax aggregation over bf16 h1 -> bf16 x2 ----------------
__global__ __launch_bounds__(64) void node1_k(const unsigned short* __restrict__ h1b,
    const float* __restrict__ aS, const float* __restrict__ aD,
    const int* __restrict__ off, const int* __restrict__ csr,
    const float* __restrict__ b1, unsigned short* __restrict__ x2b, int N){
  int n = blockIdx.x;
  int lane = threadIdx.x;
  int c = lane*2;                 // channels c, c+1
  int h = lane >> 3;              // head = c/16
  float ad = aD[n*H1+h];
  float p = __expf(lrelu(aS[n*H1+h] + ad));   // self loop
  float d = p;
  unsigned hv = *(const unsigned*)&h1b[(size_t)n*D1 + c];
  float acc0 = p*bf_lo(hv), acc1 = p*bf_hi(hv);
  int i = off[n], e = off[n+1];
  for (; i < e && (i & 3); ++i){
    int s = csr[i];
    float pp = __expf(lrelu(aS[s*H1+h] + ad));
    unsigned vv = *(const unsigned*)&h1b[(size_t)s*D1 + c];
    d += pp; acc0 += pp*bf_lo(vv); acc1 += pp*bf_hi(vv);
  }
  for (; i+8 <= e; i += 8){
    int4 ca = *(const int4*)&csr[i];
    int4 cb = *(const int4*)&csr[i+4];
    int s[8] = {ca.x,ca.y,ca.z,ca.w,cb.x,cb.y,cb.z,cb.w};
    float a[8]; unsigned v[8];
    #pragma unroll
    for (int u=0;u<8;u++) a[u] = aS[s[u]*H1+h];
    #pragma unroll
    for (int u=0;u<8;u++) v[u] = *(const unsigned*)&h1b[(size_t)s[u]*D1 + c];
    #pragma unroll
    for (int u=0;u<8;u++){
      float pp = __expf(lrelu(a[u]+ad));
      d += pp; acc0 += pp*bf_lo(v[u]); acc1 += pp*bf_hi(v[u]);
    }
  }
  for (; i < e; ++i){
    int s = csr[i];
    float pp = __expf(lrelu(aS[s*H1+h] + ad));
    unsigned vv = *(const unsigned*)&h1b[(size_t)s*D1 + c];
    d += pp; acc0 += pp*bf_lo(vv); acc1 += pp*bf_hi(vv);
  }
  float inv = 1.f/d;
  float o0 = elu(acc0*inv + b1[c]);
  float o1 = elu(acc1*inv + b1[c+1]);
  unsigned pk = (unsigned)f2bf(o0) | ((unsigned)f2bf(o1) << 16);
  *(unsigned*)&x2b[(size_t)n*D1 + c] = pk;
}

// ---------------- node2: 3 nodes per wave (20 lanes each) ----------------
__global__ __launch_bounds__(64) void node2_k(const unsigned short* __restrict__ h2b,
    const float* __restrict__ aS2, const float* __restrict__ aD2,
    const int* __restrict__ off, const int* __restrict__ csr,
    const float* __restrict__ b2, float* __restrict__ out, int N){
  int lane = threadIdx.x;
  int g = lane / 20;              // 0..3 (g==3 idle)
  int l = lane - g*20;            // 0..19
  int n = blockIdx.x*3 + g;
  if (g >= 3 || n >= N) return;
  int c = l*2;
  float ad = aD2[n];
  float ps = __expf(lrelu(aS2[n] + ad));   // self loop
  float d = ps;
  unsigned v0 = *(const unsigned*)&h2b[(size_t)n*D2 + c];
  float acc0 = ps*bf_lo(v0), acc1 = ps*bf_hi(v0);
  int i = off[n], e = off[n+1];
  for (; i < e && (i & 3); ++i){
    int s = csr[i];
    float pp = __expf(lrelu(aS2[s] + ad));
    unsigned vv = *(const unsigned*)&h2b[(size_t)s*D2 + c];
    d += pp; acc0 += pp*bf_lo(vv); acc1 += pp*bf_hi(vv);
  }
  for (; i+8 <= e; i += 8){
    int4 ca = *(const int4*)&csr[i];
    int4 cb = *(const int4*)&csr[i+4];
    int s[8] = {ca.x,ca.y,ca.z,ca.w,cb.x,cb.y,cb.z,cb.w};
    float a[8]; unsigned v[8];
    #pragma unroll
    for (int u=0;u<8;u++) a[u] = aS2[s[u]];
    #pragma unroll
    for (int u=0;u<8;u++) v[u] = *(const unsigned*)&h2b[(size_t)s[u]*D2 + c];
    #pragma unroll
    for (int u=0;u<8;u++){
      float pp = __expf(lrelu(a[u]+ad));
      d += pp; acc0 += pp*bf_lo(v[u]); acc1 += pp*bf_hi(v[u]);
    }
  }
  for (; i < e; ++i){
    int s = csr[i];
    float pp = __expf(lrelu(aS2[s] + ad));
    unsigned vv = *(const unsigned*)&h2b[(size_t)s*D2 + c];
    d += pp; acc0 += pp*bf_lo(vv); acc1 += pp*bf_hi(vv);
  }
  float inv = 1.f/d;
  float2 o;
  o.x = acc0*inv + b2[c];
  o.y = acc1*inv + b2[c+1];
  *(float2*)&out[(size_t)n*D2 + c] = o;
}

extern "C" void kernel_launch(void* const* d_in, const int* in_sizes, int n_in,
                              void* d_out, int out_size, void* d_ws, size_t ws_size,
                              hipStream_t stream){
  const float* x     = (const float*)d_in[0];
  const int*   ei    = (const int*)d_in[1];
  const float* W1    = (const float*)d_in[2];
  const float* attS1 = (const float*)d_in[3];
  const float* attD1 = (const float*)d_in[4];
  const float* b1    = (const float*)d_in[5];
  const float* W2    = (const float*)d_in[6];
  const float* attS2 = (const float*)d_in[7];
  const float* attD2 = (const float*)d_in[8];
  const float* b2    = (const float*)d_in[9];
  float* out = (float*)d_out;

  int N = in_sizes[0] / FIN;   // 50000
  int E = in_sizes[1] / 2;     // 1600000
  const int* src = ei;
  const int* dst = ei + E;
  int NB = (N + BWIDTH - 1) >> BW_LOG;    // 196

  char* ws = (char*)d_ws;
  size_t o = 0;
  auto alloc = [&](size_t bytes) -> void* {
    void* p = ws + o;
    o += (bytes + 255) & ~size_t(255);
    return p;
  };
  unsigned short* h1b = (unsigned short*)alloc((size_t)N*D1*sizeof(unsigned short));
  unsigned short* x2b = (unsigned short*)alloc((size_t)N*D1*sizeof(unsigned short));
  unsigned short* h2b = (unsigned short*)alloc((size_t)N*D2*sizeof(unsigned short));
  float* aS1   = (float*)alloc((size_t)N*H1*sizeof(float));
  float* aD1   = (float*)alloc((size_t)N*H1*sizeof(float));
  float* aS2   = (float*)alloc((size_t)N*sizeof(float));
  float* aD2   = (float*)alloc((size_t)N*sizeof(float));
  int*   off   = (int*)alloc((size_t)(N+1)*sizeof(int));
  int*   csr   = (int*)alloc((size_t)E*sizeof(int));
  int*   gcur  = (int*)alloc((size_t)256*sizeof(int));
  int*   bucketEdges = (int*)alloc((size_t)NB*CAP*sizeof(int));
  unsigned short* W1T = (unsigned short*)alloc((size_t)D1*FIN*sizeof(unsigned short));
  unsigned short* W2T = (unsigned short*)alloc((size_t)D2P*D1*sizeof(unsigned short));

  int G1 = (N + 63) / 64;      // gemm1 blocks = 782

  f1_k<<<153, 256, 0, stream>>>(W1, W1T, W2, W2T, gcur, NB);
  f3_k<<<G1 + B1, 256, 0, stream>>>(x, W1T, attS1, attD1, h1b, aS1, aD1, N, G1,
                                    src, dst, E, NB, gcur, bucketEdges);
  p2_k<<<NB, BWIDTH, 0, stream>>>(bucketEdges, gcur, NB, off, csr, N);
  node1_k<<<N, 64, 0, stream>>>(h1b, aS1, aD1, off, csr, b1, x2b, N);
  gemm2_mfma<<<(N+127)/128, 256, 0, stream>>>(x2b, W2T, attS2, attD2, h2b, aS2, aD2, N);
  node2_k<<<(N+2)/3, 64, 0, stream>>>(h2b, aS2, aD2, off, csr, b2, out, N);
}